// Round 1
// baseline (114.381 us; speedup 1.0000x reference)
//
#include <hip/hip_runtime.h>
#include <hip/hip_bf16.h>

#define NE 9          // experts
#define NDIM 1024     // feature dim
#define BM 128
#define BN 128
#define BK 64
#define LDSS 72       // 64 + 8 pad (ushorts) -> 144B row stride, 2-way bank alias (free)

typedef __attribute__((ext_vector_type(8))) short bf16x8;
typedef __attribute__((ext_vector_type(4))) float f32x4;
typedef unsigned short ushort_t;
typedef unsigned int uint_t;

__device__ inline uint_t pack2_bf16(float a, float b) {
    __hip_bfloat162 h = __float22bfloat162_rn(float2{a, b});
    return *reinterpret_cast<uint_t*>(&h);
}

// ---------------- bucket samples by expert ----------------
__global__ void bucket_kernel(const int* __restrict__ sidx,
                              int* __restrict__ perm,
                              int* __restrict__ offsets, int nB) {
    __shared__ int cnt[NE];
    __shared__ int cur[NE];
    int t = threadIdx.x;
    if (t < NE) cnt[t] = 0;
    __syncthreads();
    for (int i = t; i < nB; i += blockDim.x) atomicAdd(&cnt[sidx[i]], 1);
    __syncthreads();
    if (t == 0) {
        int run = 0;
        for (int e = 0; e < NE; ++e) { cur[e] = run; offsets[e] = run; run += cnt[e]; }
        offsets[NE] = run;
    }
    __syncthreads();
    for (int i = t; i < nB; i += blockDim.x) {
        int p = atomicAdd(&cur[sidx[i]], 1);
        perm[p] = i;
    }
}

// ---------------- grouped GEMM: out[perm rows] = x @ W[e]^T + b[e] ----------------
__global__ __launch_bounds__(256, 2)
void session_gemm_kernel(const float* __restrict__ x,
                         const float* __restrict__ W,
                         const float* __restrict__ bias,
                         const int* __restrict__ perm,
                         const int* __restrict__ offsets,
                         float* __restrict__ out) {
    const int e   = blockIdx.z;
    const int off = offsets[e];
    const int cnt = offsets[e + 1] - off;
    const int m0  = blockIdx.y * BM;
    if (m0 >= cnt) return;
    const int n0  = blockIdx.x * BN;

    __shared__ ushort_t As[BM][LDSS];
    __shared__ ushort_t Bs[BN][LDSS];

    const int t = threadIdx.x;

    // ---- staging decomposition: 16 lanes cover one 64-float row (256B contiguous) ----
    const int s_col = (t & 15) * 4;   // float offset within row
    const int s_row = t >> 4;         // base row (0..15), +16 per iteration

    // Pre-resolve gathered x rows for the 8 staging iterations (register-resident).
    int arow[8];
#pragma unroll
    for (int it = 0; it < 8; ++it) {
        int r  = it * 16 + s_row;
        int gm = m0 + r;
        arow[it] = (gm < cnt) ? perm[off + gm] : -1;
    }
    // W base pointer for this thread's staging lane (row n0 + s_row, col s_col)
    const float* wb0 = W + ((size_t)e * NDIM + (size_t)(n0 + s_row)) * NDIM + s_col;

    // ---- wave decomposition: 4 waves in 2x2, each owns a 64x64 output sub-tile ----
    const int wave = t >> 6;
    const int wr   = (wave >> 1) * 64;
    const int wc   = (wave & 1) * 64;
    const int lane = t & 63;
    const int fr   = lane & 15;   // fragment row/col index
    const int fq   = lane >> 4;   // quad index 0..3

    f32x4 acc[4][4];
#pragma unroll
    for (int i = 0; i < 4; ++i)
#pragma unroll
        for (int j = 0; j < 4; ++j) acc[i][j] = (f32x4)(0.0f);

    for (int k0 = 0; k0 < NDIM; k0 += BK) {
        // ---- stage A (gathered x rows) and B (W rows), f32 -> bf16 ----
#pragma unroll
        for (int it = 0; it < 8; ++it) {
            int row = it * 16 + s_row;
            float4 va;
            if (arow[it] >= 0)
                va = *reinterpret_cast<const float4*>(x + arow[it] * NDIM + k0 + s_col);
            else
                va = float4{0.f, 0.f, 0.f, 0.f};
            uint2 pa;
            pa.x = pack2_bf16(va.x, va.y);
            pa.y = pack2_bf16(va.z, va.w);
            *reinterpret_cast<uint2*>(&As[row][s_col]) = pa;

            float4 vb = *reinterpret_cast<const float4*>(wb0 + (size_t)it * 16 * NDIM + k0);
            uint2 pb;
            pb.x = pack2_bf16(vb.x, vb.y);
            pb.y = pack2_bf16(vb.z, vb.w);
            *reinterpret_cast<uint2*>(&Bs[row][s_col]) = pb;
        }
        __syncthreads();

        // ---- MFMA: 2 kk steps x 16 mfma each ----
#pragma unroll
        for (int kk = 0; kk < BK; kk += 32) {
            bf16x8 af[4], bf[4];
#pragma unroll
            for (int mf = 0; mf < 4; ++mf)
                af[mf] = *reinterpret_cast<const bf16x8*>(&As[wr + mf * 16 + fr][kk + fq * 8]);
#pragma unroll
            for (int nf = 0; nf < 4; ++nf)
                bf[nf] = *reinterpret_cast<const bf16x8*>(&Bs[wc + nf * 16 + fr][kk + fq * 8]);
#pragma unroll
            for (int mf = 0; mf < 4; ++mf)
#pragma unroll
                for (int nf = 0; nf < 4; ++nf)
                    acc[mf][nf] = __builtin_amdgcn_mfma_f32_16x16x32_bf16(
                        af[mf], bf[nf], acc[mf][nf], 0, 0, 0);
        }
        __syncthreads();
    }

    // ---- epilogue: bias add + scatter store ----
    float bl[4];
#pragma unroll
    for (int nf = 0; nf < 4; ++nf)
        bl[nf] = bias[e * NDIM + n0 + wc + nf * 16 + fr];

#pragma unroll
    for (int mf = 0; mf < 4; ++mf) {
#pragma unroll
        for (int j = 0; j < 4; ++j) {
            int rowg = m0 + wr + mf * 16 + fq * 4 + j;
            if (rowg < cnt) {
                int grow = perm[off + rowg];
                float* orow = out + (size_t)grow * NDIM;
#pragma unroll
                for (int nf = 0; nf < 4; ++nf) {
                    int col = n0 + wc + nf * 16 + fr;
                    orow[col] = acc[mf][nf][j] + bl[nf];
                }
            }
        }
    }
}

extern "C" void kernel_launch(void* const* d_in, const int* in_sizes, int n_in,
                              void* d_out, int out_size, void* d_ws, size_t ws_size,
                              hipStream_t stream) {
    const float* x    = (const float*)d_in[0];
    const float* W    = (const float*)d_in[1];
    const float* bias = (const float*)d_in[2];
    const int*   sidx = (const int*)d_in[3];
    float*       out  = (float*)d_out;

    const int nB = in_sizes[3];            // 4096

    int* perm    = (int*)d_ws;             // [nB]
    int* offsets = perm + nB;              // [NE+1]

    bucket_kernel<<<1, 256, 0, stream>>>(sidx, perm, offsets, nB);

    dim3 grid(NDIM / BN, (nB + BM - 1) / BM, NE);
    session_gemm_kernel<<<grid, 256, 0, stream>>>(x, W, bias, perm, offsets, out);
}

// Round 2
// 55.602 us; speedup vs baseline: 2.0571x; 2.0571x over previous
//
#include <hip/hip_runtime.h>
#include <hip/hip_bf16.h>

#define NE 9          // experts
#define NDIM 1024     // feature dim
#define BM 128
#define BN 128
#define BK 64
#define NT (NDIM / BK)   // 16 K-steps
#define LDSS 72          // 64 + 8 pad (ushorts)
#define MAX_SLOTS 40     // max sum of ceil(cnt_e/BM) = 32 + 8

typedef __attribute__((ext_vector_type(8))) short bf16x8;
typedef __attribute__((ext_vector_type(4))) float f32x4;

__device__ inline unsigned pack2_bf16(float a, float b) {
    __hip_bfloat162 h = __float22bfloat162_rn(float2{a, b});
    return *reinterpret_cast<unsigned*>(&h);
}

// ---------------- bucket samples by expert + build M-tile slot table ----------------
__global__ void bucket_kernel(const int* __restrict__ sidx,
                              int* __restrict__ perm,
                              int* __restrict__ offsets,
                              int* __restrict__ slot_e,
                              int* __restrict__ slot_m0,
                              int* __restrict__ nslots,
                              int nB) {
    __shared__ int cnt[NE];
    __shared__ int cur[NE];
    int t = threadIdx.x;
    if (t < NE) cnt[t] = 0;
    __syncthreads();
    for (int i = t; i < nB; i += blockDim.x) atomicAdd(&cnt[sidx[i]], 1);
    __syncthreads();
    if (t == 0) {
        int run = 0, s = 0;
        for (int e = 0; e < NE; ++e) {
            cur[e] = run; offsets[e] = run;
            for (int m0 = 0; m0 < cnt[e]; m0 += BM) {
                slot_e[s] = e; slot_m0[s] = m0; ++s;
            }
            run += cnt[e];
        }
        offsets[NE] = run;
        *nslots = s;
    }
    __syncthreads();
    for (int i = t; i < nB; i += blockDim.x) {
        int p = atomicAdd(&cur[sidx[i]], 1);
        perm[p] = i;
    }
}

// ---------------- grouped GEMM: out[perm rows] = x @ W[e]^T + b[e] ----------------
// 512 threads = 8 waves in 2(M)x4(N); each wave owns a 64x32 output sub-tile.
__global__ __launch_bounds__(512, 4)
void session_gemm_kernel(const float* __restrict__ x,
                         const float* __restrict__ W,
                         const float* __restrict__ bias,
                         const int* __restrict__ perm,
                         const int* __restrict__ offsets,
                         const int* __restrict__ slot_e,
                         const int* __restrict__ slot_m0,
                         const int* __restrict__ nslots,
                         float* __restrict__ out) {
    // XCD-grouped mapping: all 8 N-tiles of one M-slot land on the same XCD,
    // so the gathered x panel (512 KB) is fetched once into that XCD's L2.
    const int b    = blockIdx.x;
    const int xcd  = b & 7;
    const int ord  = b >> 3;        // 0..39: position within XCD
    const int n    = ord & 7;       // N-tile
    const int sg   = ord >> 3;      // slot group within XCD
    const int slot = xcd + 8 * sg;
    if (slot >= *nslots) return;

    const int e   = slot_e[slot];
    const int m0  = slot_m0[slot];
    const int off = offsets[e];
    const int cnt = offsets[e + 1] - off;
    const int n0  = n * BN;

    __shared__ unsigned short As[2][BM][LDSS];
    __shared__ unsigned short Bs[2][BN][LDSS];

    const int t = threadIdx.x;

    // staging decomposition: 16 threads cover one 64-f32 row chunk (float4 each)
    const int s_col = (t & 15) * 4;   // f32 col within BK
    const int s_row = t >> 4;         // 0..31, +32 per it

    // resolve gathered x rows once
    int arow[4];
#pragma unroll
    for (int it = 0; it < 4; ++it) {
        int lm = it * 32 + s_row;
        arow[it] = (m0 + lm < cnt) ? perm[off + m0 + lm] : -1;
    }
    const float* wbase = W + ((size_t)e * NDIM + (size_t)(n0 + s_row)) * NDIM + s_col;
    const float* xcol  = x + s_col;

    // wave decomposition
    const int wave = t >> 6;
    const int wr   = (wave >> 2) * 64;   // 0 or 64
    const int wc   = (wave & 3) * 32;    // 0,32,64,96
    const int lane = t & 63;
    const int fr   = lane & 15;
    const int fq   = lane >> 4;

    f32x4 acc[4][2];
#pragma unroll
    for (int i = 0; i < 4; ++i)
#pragma unroll
        for (int j = 0; j < 2; ++j) acc[i][j] = (f32x4)(0.0f);

    float4 av[4], bv[4];

#define LD_REGS(K0)                                                                 \
    do {                                                                            \
        _Pragma("unroll")                                                           \
        for (int it = 0; it < 4; ++it) {                                            \
            av[it] = (arow[it] >= 0)                                                \
                ? *reinterpret_cast<const float4*>(xcol + (size_t)arow[it] * NDIM + (K0)) \
                : float4{0.f, 0.f, 0.f, 0.f};                                       \
            bv[it] = *reinterpret_cast<const float4*>(wbase + (size_t)it * 32 * NDIM + (K0)); \
        }                                                                           \
    } while (0)

#define WR_LDS(BUF)                                                                 \
    do {                                                                            \
        _Pragma("unroll")                                                           \
        for (int it = 0; it < 4; ++it) {                                            \
            uint2 pa; pa.x = pack2_bf16(av[it].x, av[it].y);                        \
            pa.y = pack2_bf16(av[it].z, av[it].w);                                  \
            *reinterpret_cast<uint2*>(&As[BUF][it * 32 + s_row][s_col]) = pa;       \
            uint2 pb; pb.x = pack2_bf16(bv[it].x, bv[it].y);                        \
            pb.y = pack2_bf16(bv[it].z, bv[it].w);                                  \
            *reinterpret_cast<uint2*>(&Bs[BUF][it * 32 + s_row][s_col]) = pb;       \
        }                                                                           \
    } while (0)

    // prologue: tile 0 staged, tile 1 loads in flight
    LD_REGS(0);
    WR_LDS(0);
    LD_REGS(BK);
    __syncthreads();

    for (int tt = 0; tt < NT; ++tt) {
        const int curb = tt & 1;
        // write tile tt+1 into the other buffer (regs already hold it; the
        // implicit vmcnt wait covers loads issued a full iteration ago)
        if (tt + 1 < NT) WR_LDS(curb ^ 1);
        // issue tile tt+2 loads; they fly across COMPUTE + next barrier
        if (tt + 2 < NT) LD_REGS((tt + 2) * BK);

        // compute on buf[curb] (disjoint from this iter's writes; last iter's
        // barrier made tile tt's LDS writes visible)
#pragma unroll
        for (int kk = 0; kk < BK; kk += 32) {
            bf16x8 af[4], bfv[2];
#pragma unroll
            for (int mf = 0; mf < 4; ++mf)
                af[mf] = *reinterpret_cast<const bf16x8*>(&As[curb][wr + mf * 16 + fr][kk + fq * 8]);
#pragma unroll
            for (int nf = 0; nf < 2; ++nf)
                bfv[nf] = *reinterpret_cast<const bf16x8*>(&Bs[curb][wc + nf * 16 + fr][kk + fq * 8]);
#pragma unroll
            for (int mf = 0; mf < 4; ++mf)
#pragma unroll
                for (int nf = 0; nf < 2; ++nf)
                    acc[mf][nf] = __builtin_amdgcn_mfma_f32_16x16x32_bf16(
                        af[mf], bfv[nf], acc[mf][nf], 0, 0, 0);
        }
        __syncthreads();
    }

    // ---- epilogue: bias add + scatter store ----
    float bl[2];
#pragma unroll
    for (int nf = 0; nf < 2; ++nf)
        bl[nf] = bias[e * NDIM + n0 + wc + nf * 16 + fr];

#pragma unroll
    for (int mf = 0; mf < 4; ++mf) {
#pragma unroll
        for (int j = 0; j < 4; ++j) {
            int lm = wr + mf * 16 + fq * 4 + j;
            if (m0 + lm < cnt) {
                int grow = perm[off + m0 + lm];
                float* orow = out + (size_t)grow * NDIM;
#pragma unroll
                for (int nf = 0; nf < 2; ++nf) {
                    int col = n0 + wc + nf * 16 + fr;
                    orow[col] = acc[mf][nf][j] + bl[nf];
                }
            }
        }
    }
#undef LD_REGS
#undef WR_LDS
}

extern "C" void kernel_launch(void* const* d_in, const int* in_sizes, int n_in,
                              void* d_out, int out_size, void* d_ws, size_t ws_size,
                              hipStream_t stream) {
    const float* x    = (const float*)d_in[0];
    const float* W    = (const float*)d_in[1];
    const float* bias = (const float*)d_in[2];
    const int*   sidx = (const int*)d_in[3];
    float*       out  = (float*)d_out;

    const int nB = in_sizes[3];   // 4096

    int* perm    = (int*)d_ws;                 // [nB]
    int* offsets = perm + nB;                  // [NE+1]
    int* slot_e  = offsets + NE + 1;           // [MAX_SLOTS]
    int* slot_m0 = slot_e + MAX_SLOTS;         // [MAX_SLOTS]
    int* nslots  = slot_m0 + MAX_SLOTS;        // [1]

    bucket_kernel<<<1, 256, 0, stream>>>(sidx, perm, offsets, slot_e, slot_m0,
                                         nslots, nB);

    session_gemm_kernel<<<MAX_SLOTS * 8, 512, 0, stream>>>(
        x, W, bias, perm, offsets, slot_e, slot_m0, nslots, out);
}